// Round 20
// baseline (323.181 us; speedup 1.0000x reference)
//
#include <hip/hip_runtime.h>
#include <hip/hip_fp16.h>

#define BATCH 16
#define NROW 1024
#define MCOL 1024
#define DFEAT 128

// DP blocking: consumer wave owns a batch; lane t rows 16t..16t+15; 8 cols/phase
#define R_DP 16
#define C_DP 8
#define NCH (MCOL / C_DP)   // 128 chunks along j
#define PSTRIDE 194         // phase slots per batch in Dphase

#define L2E 1.4426950408889634f
#define LN2 0.6931471805599453f

typedef __attribute__((ext_vector_type(8))) short short8;
typedef __attribute__((ext_vector_type(4))) float f32x4;

__device__ inline unsigned short f2bf(float f) {  // RNE f32 -> bf16 bits
  unsigned u = __float_as_uint(f);
  return (unsigned short)((u + 0x7fff + ((u >> 16) & 1)) >> 16);
}

// ---------------------------------------------------------------------------
// Kernel 1: normalize rows and emit bf16 copies. One wave per row.
// ---------------------------------------------------------------------------
__global__ __launch_bounds__(256) void norm_kernel(
    const float* __restrict__ x, const float* __restrict__ y,
    unsigned short* __restrict__ xnb, unsigned short* __restrict__ ynb) {
  int row = blockIdx.x * 4 + (threadIdx.x >> 6);
  int lane = threadIdx.x & 63;
  const float* src;
  unsigned short* dst;
  if (row < BATCH * NROW) {
    src = x + (size_t)row * DFEAT;
    dst = xnb + (size_t)row * DFEAT;
  } else {
    int r2 = row - BATCH * NROW;
    src = y + (size_t)r2 * DFEAT;
    dst = ynb + (size_t)r2 * DFEAT;
  }
  float2 v = *(const float2*)(src + lane * 2);
  float s = v.x * v.x + v.y * v.y;
  #pragma unroll
  for (int o = 32; o > 0; o >>= 1) s += __shfl_xor(s, o, 64);
  float inv = 1.0f / (sqrtf(s) + 1e-8f);
  unsigned short b0 = f2bf(v.x * inv), b1 = f2bf(v.y * inv);
  *(unsigned*)(dst + lane * 2) = (unsigned)b0 | ((unsigned)b1 << 16);
}

// ---------------------------------------------------------------------------
// Kernel 2: MFMA distance GEMM, phase-major fp16 output (r13 layout):
// Dphase[b][p][r][lane][k], p = (j>>3) + (i>>4), r = i&15, k = j&7.
// ---------------------------------------------------------------------------
__global__ __launch_bounds__(256) void dist_kernel(
    const unsigned short* __restrict__ xnb, const unsigned short* __restrict__ ynb,
    __half* __restrict__ Dphase) {
  __shared__ __align__(16) unsigned char xsb[128 * 256];
  __shared__ __align__(16) unsigned char ysb[128 * 256];

  int b = blockIdx.z, ti0 = blockIdx.y, tj0 = blockIdx.x;
  int I0 = ti0 * 128, J0 = tj0 * 128;
  int tid = threadIdx.x;

  const uint4* xsrc = (const uint4*)(xnb + (size_t)(b * NROW + I0) * DFEAT);
  const uint4* ysrc = (const uint4*)(ynb + (size_t)(b * MCOL + J0) * DFEAT);
  #pragma unroll
  for (int it = 0; it < 8; ++it) {
    int idx = tid + it * 256;
    int row = idx >> 4, cb = (idx & 15) * 16;
    int swz = row * 256 + (cb ^ ((row & 7) << 4));
    *(uint4*)&xsb[swz] = xsrc[idx];
    *(uint4*)&ysb[swz] = ysrc[idx];
  }
  __syncthreads();

  int wid = tid >> 6, lane = tid & 63;
  int wi = wid >> 1, wj = wid & 1;
  int lr = lane & 15, lk = lane >> 4;

  f32x4 acc[4][4] = {};
  #pragma unroll
  for (int ks = 0; ks < 4; ++ks) {
    int cb = ks * 64 + lk * 16;
    short8 af[4], bf[4];
    #pragma unroll
    for (int ti = 0; ti < 4; ++ti) {
      int row = wi * 64 + ti * 16 + lr;
      af[ti] = *(short8*)&xsb[row * 256 + (cb ^ ((row & 7) << 4))];
    }
    #pragma unroll
    for (int tj = 0; tj < 4; ++tj) {
      int row = wj * 64 + tj * 16 + lr;
      bf[tj] = *(short8*)&ysb[row * 256 + (cb ^ ((row & 7) << 4))];
    }
    #pragma unroll
    for (int ti = 0; ti < 4; ++ti)
      #pragma unroll
      for (int tj = 0; tj < 4; ++tj)
        acc[ti][tj] = __builtin_amdgcn_mfma_f32_16x16x32_bf16(
            af[ti], bf[tj], acc[ti][tj], 0, 0, 0);
  }

  #pragma unroll
  for (int ti = 0; ti < 4; ++ti) {
    int gi0 = I0 + wi * 64 + ti * 16;
    int l = gi0 >> 4;
    #pragma unroll
    for (int tj = 0; tj < 4; ++tj) {
      int gj = J0 + wj * 64 + tj * 16 + lr;
      int c = gj >> 3, k = gj & 7;
      int p = c + l;
      #pragma unroll
      for (int v = 0; v < 4; ++v) {
        int r = lk * 4 + v;
        float d = 1.0f - acc[ti][tj][v];
        size_t off = ((((size_t)b * PSTRIDE + p) * R_DP + r) * 64 + l) * C_DP + k;
        Dphase[off] = __float2half(exp2f(-d * L2E));
      }
    }
  }
}

// ---------------------------------------------------------------------------
// Kernel 3: 4-producer / 1-consumer soft-DTW DP. 16 blocks x 320 threads:
//   waves 1-4 (producers): 4 rows each (SYMMETRIC ISSUE4 — r19-validated
//     shape; r18's NaN came with asymmetric macros). 4 KB/phase each; per-CU
//     aggregate ~13 B/cyc matches the r14-measured per-CU delivery ceiling.
//   wave 0 (consumer): r19's verbatim DP body.
// Handshake: busy-wait volatile LDS polls (r19's s_sleep(8) = 512-cyc wake
// quantization was inflating cadence); 8-slot ring (128 KB) for slack.
// Protocol identical to r17/r19 (validated): data ds_writes -> lgkmcnt(0)
// -> flag; slot p+8 written only after cc >= p+1.
// ---------------------------------------------------------------------------

// A = f16(lo/hi of h) * s      (fzero VGPR)
#define MIXMUL_LO(A, h, s) \
  asm("v_fma_mix_f32 %0, %1, %2, %3 op_sel_hi:[1,0,0]" : "=v"(A) : "v"(h), "v"(s), "v"(fzero))
#define MIXMUL_HI(A, h, s) \
  asm("v_fma_mix_f32 %0, %1, %2, %3 op_sel:[1,0,0] op_sel_hi:[1,0,0]" : "=v"(A) : "v"(h), "v"(s), "v"(fzero))
#define MIXFMA_LO(lf, h, a) \
  asm("v_fma_mix_f32 %0, %1, %2, %3 op_sel_hi:[1,0,0]" : "=v"(lf) : "v"(h), "v"(lf), "v"(a))
#define MIXFMA_HI(lf, h, a) \
  asm("v_fma_mix_f32 %0, %1, %2, %3 op_sel:[1,0,0] op_sel_hi:[1,0,0]" : "=v"(lf) : "v"(h), "v"(lf), "v"(a))

__device__ __forceinline__ float shup(float x, bool edge) {
  int xi = __float_as_int(x);
  int sh = __builtin_amdgcn_update_dpp(xi, xi, 0x111, 0xF, 0xF, false); // row_shr:1
  int bc = __builtin_amdgcn_update_dpp(xi, xi, 0x142, 0xF, 0xF, false); // row_bcast15
  return __int_as_float(edge ? bc : sh);
}

template<bool GUARDED>
__device__ __forceinline__ void dtw_phase_l(int c, int t, bool edge,
    const uint4 (*slot)[64], float* carry, float (&B)[9], float& O, float fzero) {
  float U[9];
  #pragma unroll
  for (int k = 0; k < 9; ++k) U[k] = shup(B[k], edge);
  float Oin = shup(O, edge);
  if (t == 0) {
    #pragma unroll
    for (int k = 0; k < 9; ++k) U[k] = 0.0f;
    if (GUARDED && c == 0) U[0] = 1.0f;   // E[0][0] = exp(-0)
    Oin = O;
  }
  bool act = GUARDED ? ((unsigned)c < 128u) : true;
  if (act) {
    if (GUARDED && c == 0) O = Oin;       // adopt neighbor's frame
    float sc = exp2f((O - Oin) * L2E);
    #pragma unroll
    for (int k = 0; k < 9; ++k) U[k] *= sc;

    #pragma unroll
    for (int r = 0; r < R_DP; ++r) {
      uint4 d = slot[r][t];               // ds_read_b128
      unsigned dw[4] = {d.x, d.y, d.z, d.w};
      float S[8], A[8];
      #pragma unroll
      for (int k = 0; k < 8; ++k) S[k] = U[k] + U[k + 1];
      #pragma unroll
      for (int q = 0; q < 4; ++q) {
        MIXMUL_LO(A[2 * q],     dw[q], S[2 * q]);
        MIXMUL_HI(A[2 * q + 1], dw[q], S[2 * q + 1]);
      }
      float oldc = carry[r], lf = oldc;
      float V[8];
      #pragma unroll
      for (int q = 0; q < 4; ++q) {
        MIXFMA_LO(lf, dw[q], A[2 * q]);     V[2 * q] = lf;
        MIXFMA_HI(lf, dw[q], A[2 * q + 1]); V[2 * q + 1] = lf;
      }
      U[0] = oldc;
      #pragma unroll
      for (int k = 1; k <= 8; ++k) U[k] = V[k - 1];
      carry[r] = lf;
    }

    // renorm: E *= 2^-ex  =>  O -= ex*ln2 ; window [-20,+12]; rep>0 guard
    float rep = carry[R_DP - 1];
    if (rep > 0.0f) {
      int ex = (int)((__float_as_uint(rep) >> 23) & 0xFF) - 127;
      if ((ex < -20 || ex > 12) && ex < 128) {
        float s = __uint_as_float((unsigned)(127 - ex) << 23);  // 2^-ex
        #pragma unroll
        for (int r = 0; r < R_DP; ++r) carry[r] *= s;
        #pragma unroll
        for (int k = 0; k < 9; ++k) U[k] *= s;
        O -= (float)ex * LN2;
      }
    }
    #pragma unroll
    for (int k = 0; k < 9; ++k) B[k] = U[k];
  }
}

#define GLP(Lr, SB, OFF) \
  asm volatile("global_load_dwordx4 %0, %1, %2 offset:" OFF : "=v"(Lr) : "v"(voff), "s"(SB));

#define ISSUE4(L, S0)                                            \
  GLP(L[0], S0, "0")    GLP(L[1], S0, "1024")                    \
  GLP(L[2], S0, "2048") GLP(L[3], S0, "3072")

// one producer phase: issue slab PH+1 into NXT, commit CUR (slab PH)
#define PSTEP(PH, CUR, NXT)                                                  \
  {                                                                          \
    int pn = (PH) + 1 > 190 ? 190 : (PH) + 1;                                \
    const char* s0 = base + ((size_t)pn << 14);                              \
    if ((unsigned)(pn - t) < 128u) { ISSUE4(NXT, s0) }                       \
    asm volatile("s_waitcnt vmcnt(4)" ::: "memory");                         \
    __builtin_amdgcn_sched_barrier(0);                                       \
    while ((int)((PH) - (int)*cc) >= 8) __builtin_amdgcn_s_sleep(1);         \
    if ((unsigned)((PH) - t) < 128u) {                                       \
      _Pragma("unroll")                                                      \
      for (int r = 0; r < 4; ++r) ring[(PH) & 7][RS + r][t] = CUR[r];        \
    }                                                                        \
    asm volatile("s_waitcnt lgkmcnt(0)" ::: "memory");                       \
    if (t == 0) *myflag = (PH) + 1;                                          \
  }

__device__ __forceinline__ void producer(const char* g, int t, int RS,
    volatile unsigned* myflag, volatile unsigned* cc,
    uint4 (*ring)[R_DP][64]) {
  int voff = t * 16;
  const char* base = g + RS * 1024;     // rows RS..RS+3, row stride 1024B

  uint4 A[4], Bb[4];
  {
    const char* s0 = base;
    if ((unsigned)(0 - t) < 128u) { ISSUE4(A, s0) }
  }
  for (int p = 0; p < 192; p += 2) {
    PSTEP(p, A, Bb)
    PSTEP(p + 1, Bb, A)
  }
  asm volatile("s_waitcnt vmcnt(0)" ::: "memory");
}

__global__ __launch_bounds__(320, 1) void dtw_kernel(
    const __half* __restrict__ Dphase, float* __restrict__ out) {
  __shared__ __align__(16) uint4 ring[8][R_DP][64];   // 128 KB
  __shared__ volatile unsigned pc[4];
  __shared__ volatile unsigned cc;

  int b = blockIdx.x;
  int tid = threadIdx.x;
  int w = __builtin_amdgcn_readfirstlane(tid >> 6);
  int t = tid & 63;
  float fzero = 0.0f;

  if (tid == 0) { pc[0] = 0; pc[1] = 0; pc[2] = 0; pc[3] = 0; cc = 0; }
  __syncthreads();

  const char* g = (const char*)Dphase + (size_t)b * PSTRIDE * 16384;

  if (w == 1) {
    producer(g, t, 0, &pc[0], &cc, ring);
  } else if (w == 2) {
    producer(g, t, 4, &pc[1], &cc, ring);
  } else if (w == 3) {
    producer(g, t, 8, &pc[2], &cc, ring);
  } else if (w == 4) {
    producer(g, t, 12, &pc[3], &cc, ring);
  } else {
    // ----------------- CONSUMER (wave 0) -----------------
    const bool edge = (t != 0) && ((t & 15) == 0);
    float carry[R_DP];
    #pragma unroll
    for (int r = 0; r < R_DP; ++r) carry[r] = 0.0f;
    float B[9] = {};
    float O = 0.0f;

    #define CONSUME(P, G)                                                    \
      {                                                                      \
        while ((int)pc[0] < (P) + 1 || (int)pc[1] < (P) + 1 ||               \
               (int)pc[2] < (P) + 1 || (int)pc[3] < (P) + 1) {}              \
        asm volatile("s_waitcnt lgkmcnt(0)" ::: "memory");                   \
        __builtin_amdgcn_sched_barrier(0);                                   \
        dtw_phase_l<G>((P) - t, t, edge, ring[(P) & 7], carry, B, O, fzero); \
        asm volatile("s_waitcnt lgkmcnt(0)" ::: "memory");                   \
        if (t == 0) cc = (P) + 1;                                            \
      }

    for (int p = 0; p < 64; ++p)    CONSUME(p, true)
    for (int p = 64; p < 128; ++p)  CONSUME(p, false)
    for (int p = 128; p < 191; ++p) CONSUME(p, true)

    if (t == 63) out[b] = O - logf(carry[R_DP - 1]);  // R[N][M]
    #undef CONSUME
  }
}

// ---------------------------------------------------------------------------
extern "C" void kernel_launch(void* const* d_in, const int* in_sizes, int n_in,
                              void* d_out, int out_size, void* d_ws, size_t ws_size,
                              hipStream_t stream) {
  const float* x = (const float*)d_in[0];
  const float* y = (const float*)d_in[1];
  float* out = (float*)d_out;

  char* ws = (char*)d_ws;
  __half* Dphase = (__half*)ws;
  size_t dp_bytes = (size_t)BATCH * PSTRIDE * 16384;   // ~50.9 MB
  unsigned short* xnb = (unsigned short*)(ws + dp_bytes);          // 4 MB
  unsigned short* ynb = xnb + (size_t)BATCH * NROW * DFEAT;        // 4 MB

  norm_kernel<<<(2 * BATCH * NROW) / 4, 256, 0, stream>>>(x, y, xnb, ynb);
  dist_kernel<<<dim3(MCOL / 128, NROW / 128, BATCH), 256, 0, stream>>>(
      xnb, ynb, Dphase);
  dtw_kernel<<<BATCH, 320, 0, stream>>>(Dphase, out);
}

// Round 21
// 298.095 us; speedup vs baseline: 1.0842x; 1.0842x over previous
//
#include <hip/hip_runtime.h>
#include <hip/hip_fp16.h>

#define BATCH 16
#define NROW 1024
#define MCOL 1024
#define DFEAT 128

// DP blocking: 2 waves/batch; lane-unit l2 (=64w+t) owns rows 8*l2..+7
#define R_DP 8
#define C_DP 8
#define NCH (MCOL / C_DP)   // 128 chunks along j
#define NPH2 255            // phases 0..254 (128 chunks + 128 units - 1)
#define BATCH_BYTES 2097152 // compact parallelogram: exactly 2 MB per batch

#define L2E 1.4426950408889634f
#define LN2 0.6931471805599453f

typedef __attribute__((ext_vector_type(8))) short short8;
typedef __attribute__((ext_vector_type(4))) float f32x4;

__device__ inline unsigned short f2bf(float f) {  // RNE f32 -> bf16 bits
  unsigned u = __float_as_uint(f);
  return (unsigned short)((u + 0x7fff + ((u >> 16) & 1)) >> 16);
}

// compact layout helpers: slab p holds units l2 in [l2min(p), min(p,127)],
// row-major [r2][l2-l2min][k] fp16; width w(p), prefix sbase(p) in bytes.
__device__ __forceinline__ int wphase(int p) { return p < 128 ? p + 1 : 255 - p; }
__device__ __forceinline__ int l2minf(int p) { return p > 127 ? p - 127 : 0; }
__device__ __forceinline__ int sbase(int p) {
  return p <= 128 ? 64 * p * (p + 1)
                  : BATCH_BYTES - 64 * (255 - p) * (256 - p);
}

// ---------------------------------------------------------------------------
// Kernel 1: normalize rows and emit bf16 copies. One wave per row.
// ---------------------------------------------------------------------------
__global__ __launch_bounds__(256) void norm_kernel(
    const float* __restrict__ x, const float* __restrict__ y,
    unsigned short* __restrict__ xnb, unsigned short* __restrict__ ynb) {
  int row = blockIdx.x * 4 + (threadIdx.x >> 6);
  int lane = threadIdx.x & 63;
  const float* src;
  unsigned short* dst;
  if (row < BATCH * NROW) {
    src = x + (size_t)row * DFEAT;
    dst = xnb + (size_t)row * DFEAT;
  } else {
    int r2 = row - BATCH * NROW;
    src = y + (size_t)r2 * DFEAT;
    dst = ynb + (size_t)r2 * DFEAT;
  }
  float2 v = *(const float2*)(src + lane * 2);
  float s = v.x * v.x + v.y * v.y;
  #pragma unroll
  for (int o = 32; o > 0; o >>= 1) s += __shfl_xor(s, o, 64);
  float inv = 1.0f / (sqrtf(s) + 1e-8f);
  unsigned short b0 = f2bf(v.x * inv), b1 = f2bf(v.y * inv);
  *(unsigned*)(dst + lane * 2) = (unsigned)b0 | ((unsigned)b1 << 16);
}

// ---------------------------------------------------------------------------
// Kernel 2: MFMA distance GEMM; epilogue stores exp(-(1-dot)) fp16 into the
// compact 8-row-unit layout: cell (i,j): l2=i>>3, r2=i&7, c=j>>3, k=j&7,
// p=c+l2; addr = sbase(p) + r2*w(p)*16 + (l2-l2min(p))*16 + k*2.
// ---------------------------------------------------------------------------
__global__ __launch_bounds__(256) void dist_kernel(
    const unsigned short* __restrict__ xnb, const unsigned short* __restrict__ ynb,
    char* __restrict__ Dc) {
  __shared__ __align__(16) unsigned char xsb[128 * 256];
  __shared__ __align__(16) unsigned char ysb[128 * 256];

  int b = blockIdx.z, ti0 = blockIdx.y, tj0 = blockIdx.x;
  int I0 = ti0 * 128, J0 = tj0 * 128;
  int tid = threadIdx.x;

  const uint4* xsrc = (const uint4*)(xnb + (size_t)(b * NROW + I0) * DFEAT);
  const uint4* ysrc = (const uint4*)(ynb + (size_t)(b * MCOL + J0) * DFEAT);
  #pragma unroll
  for (int it = 0; it < 8; ++it) {
    int idx = tid + it * 256;
    int row = idx >> 4, cb = (idx & 15) * 16;
    int swz = row * 256 + (cb ^ ((row & 7) << 4));
    *(uint4*)&xsb[swz] = xsrc[idx];
    *(uint4*)&ysb[swz] = ysrc[idx];
  }
  __syncthreads();

  int wid = tid >> 6, lane = tid & 63;
  int wi = wid >> 1, wj = wid & 1;
  int lr = lane & 15, lk = lane >> 4;

  f32x4 acc[4][4] = {};
  #pragma unroll
  for (int ks = 0; ks < 4; ++ks) {
    int cb = ks * 64 + lk * 16;
    short8 af[4], bf[4];
    #pragma unroll
    for (int ti = 0; ti < 4; ++ti) {
      int row = wi * 64 + ti * 16 + lr;
      af[ti] = *(short8*)&xsb[row * 256 + (cb ^ ((row & 7) << 4))];
    }
    #pragma unroll
    for (int tj = 0; tj < 4; ++tj) {
      int row = wj * 64 + tj * 16 + lr;
      bf[tj] = *(short8*)&ysb[row * 256 + (cb ^ ((row & 7) << 4))];
    }
    #pragma unroll
    for (int ti = 0; ti < 4; ++ti)
      #pragma unroll
      for (int tj = 0; tj < 4; ++tj)
        acc[ti][tj] = __builtin_amdgcn_mfma_f32_16x16x32_bf16(
            af[ti], bf[tj], acc[ti][tj], 0, 0, 0);
  }

  char* Db = Dc + (size_t)b * BATCH_BYTES;
  #pragma unroll
  for (int ti = 0; ti < 4; ++ti) {
    int gi0 = I0 + wi * 64 + ti * 16 + lk * 4;  // 4-aligned; l2 const over v
    int l2 = gi0 >> 3, r2b = gi0 & 7;
    #pragma unroll
    for (int tj = 0; tj < 4; ++tj) {
      int gj = J0 + wj * 64 + tj * 16 + lr;
      int c = gj >> 3, k = gj & 7;
      int p = c + l2;
      int wv = wphase(p), l2m = l2minf(p);
      char* slot = Db + sbase(p) + r2b * (wv << 4) + ((l2 - l2m) << 4) + (k << 1);
      int rs = wv << 4;
      #pragma unroll
      for (int v = 0; v < 4; ++v) {
        float d = 1.0f - acc[ti][tj][v];
        *(__half*)(slot + v * rs) = __float2half(exp2f(-d * L2E));
      }
    }
  }
}

// ---------------------------------------------------------------------------
// Kernel 3: 2-wave soft-DTW DP (16 blocks x 128 threads). Lane-unit
// l2 = 64*w + t owns rows 8*l2..+7; phase P handles chunk c = P - l2.
// Per-wave delivery: 8 load-instr/phase (r16 evidence: delivery throughput
// is per-wave-bounded ~190cyc/instr and splits across waves; W=2 balances
// delivery (1520cyc) vs phases (255) vs one seam). Intra-wave handoff: DPP
// (r13). Seam: LDS bnd[parity][10] + 1 barrier/phase (r16-validated
// protocol). Compute: r13's verbatim 8-row body. Wave-uniform doissue keeps
// vmcnt exact; boundary phases fall back to vmcnt(0).
// ---------------------------------------------------------------------------

// A = f16(lo/hi of h) * s      (fzero VGPR)
#define MIXMUL_LO(A, h, s) \
  asm("v_fma_mix_f32 %0, %1, %2, %3 op_sel_hi:[1,0,0]" : "=v"(A) : "v"(h), "v"(s), "v"(fzero))
#define MIXMUL_HI(A, h, s) \
  asm("v_fma_mix_f32 %0, %1, %2, %3 op_sel:[1,0,0] op_sel_hi:[1,0,0]" : "=v"(A) : "v"(h), "v"(s), "v"(fzero))
#define MIXFMA_LO(lf, h, a) \
  asm("v_fma_mix_f32 %0, %1, %2, %3 op_sel_hi:[1,0,0]" : "=v"(lf) : "v"(h), "v"(lf), "v"(a))
#define MIXFMA_HI(lf, h, a) \
  asm("v_fma_mix_f32 %0, %1, %2, %3 op_sel:[1,0,0] op_sel_hi:[1,0,0]" : "=v"(lf) : "v"(h), "v"(lf), "v"(a))

__device__ __forceinline__ float shup(float x, bool edge) {
  int xi = __float_as_int(x);
  int sh = __builtin_amdgcn_update_dpp(xi, xi, 0x111, 0xF, 0xF, false); // row_shr:1
  int bc = __builtin_amdgcn_update_dpp(xi, xi, 0x142, 0xF, 0xF, false); // row_bcast15
  return __int_as_float(edge ? bc : sh);
}

__device__ __forceinline__ void dtw_phase8(int c, int t, bool isw0, bool edge,
    const uint4* L, float* carry, float (&B)[9], float& O, float fzero,
    const float* bndPrev) {
  float U[9];
  #pragma unroll
  for (int k = 0; k < 9; ++k) U[k] = shup(B[k], edge);
  float Oin = shup(O, edge);
  if (t == 0) {
    if (isw0) {
      #pragma unroll
      for (int k = 0; k < 9; ++k) U[k] = 0.0f;
      U[0] = (c == 0) ? 1.0f : 0.0f;    // E[0][0] = exp(-0)
      Oin = O;
    } else {
      #pragma unroll
      for (int k = 0; k < 9; ++k) U[k] = bndPrev[k];
      Oin = bndPrev[9];
    }
  }
  if ((unsigned)c < 128u) {
    if (c == 0) O = Oin;                // adopt neighbor's frame at activation
    float sc = exp2f((O - Oin) * L2E);
    #pragma unroll
    for (int k = 0; k < 9; ++k) U[k] *= sc;

    #pragma unroll
    for (int r = 0; r < R_DP; ++r) {
      uint4 d = L[r];
      unsigned dw[4] = {d.x, d.y, d.z, d.w};
      float S[8], A[8];
      #pragma unroll
      for (int k = 0; k < 8; ++k) S[k] = U[k] + U[k + 1];
      #pragma unroll
      for (int q = 0; q < 4; ++q) {
        MIXMUL_LO(A[2 * q],     dw[q], S[2 * q]);
        MIXMUL_HI(A[2 * q + 1], dw[q], S[2 * q + 1]);
      }
      float oldc = carry[r], lf = oldc;
      float V[8];
      #pragma unroll
      for (int q = 0; q < 4; ++q) {
        MIXFMA_LO(lf, dw[q], A[2 * q]);     V[2 * q] = lf;
        MIXFMA_HI(lf, dw[q], A[2 * q + 1]); V[2 * q + 1] = lf;
      }
      U[0] = oldc;
      #pragma unroll
      for (int k = 1; k <= 8; ++k) U[k] = V[k - 1];
      carry[r] = lf;
    }

    // renorm: E *= 2^-ex  =>  O -= ex*ln2 ; window [-20,+12]; rep>0 guard
    float rep = carry[R_DP - 1];
    if (rep > 0.0f) {
      int ex = (int)((__float_as_uint(rep) >> 23) & 0xFF) - 127;
      if ((ex < -20 || ex > 12) && ex < 128) {
        float s = __uint_as_float((unsigned)(127 - ex) << 23);  // 2^-ex
        #pragma unroll
        for (int r = 0; r < R_DP; ++r) carry[r] *= s;
        #pragma unroll
        for (int k = 0; k < 9; ++k) U[k] *= s;
        O -= (float)ex * LN2;
      }
    }
    #pragma unroll
    for (int k = 0; k < 9; ++k) B[k] = U[k];
  }
}

#define GLP(Lr, SB) \
  asm volatile("global_load_dwordx4 %0, %1, %2" : "=v"(Lr) : "v"(voff), "s"(SB));

#define ISSUE8()                                                 \
  GLP(L[0], sb0) GLP(L[1], sb1) GLP(L[2], sb2) GLP(L[3], sb3)    \
  GLP(L[4], sb4) GLP(L[5], sb5) GLP(L[6], sb6) GLP(L[7], sb7)

__global__ __launch_bounds__(128, 1) void dtw_kernel(
    const char* __restrict__ Dc, float* __restrict__ out) {
  __shared__ float bnd[2][10];
  int b = blockIdx.x;
  int tid = threadIdx.x;
  int w = __builtin_amdgcn_readfirstlane(tid >> 6);
  int t = tid & 63;
  int l2 = (w << 6) + t;
  const bool edge = (t != 0) && ((t & 15) == 0);
  float fzero = 0.0f;
  int vbase = l2 << 4;

  if (tid < 20) ((float*)bnd)[tid] = 0.0f;
  __syncthreads();

  const char* g = Dc + (size_t)b * BATCH_BYTES;

  float carry[R_DP];
  #pragma unroll
  for (int r = 0; r < R_DP; ++r) carry[r] = 0.0f;
  float B[9] = {};
  float O = 0.0f;
  uint4 L[R_DP];

  // prologue: slab 0 (w(0)=1, l2min=0) — wave0 only, lane-masked
  if (w == 0) {
    const char* sb0 = g,       * sb1 = g + 16,  * sb2 = g + 32,  * sb3 = g + 48;
    const char* sb4 = g + 64,  * sb5 = g + 80,  * sb6 = g + 96,  * sb7 = g + 112;
    int voff = vbase;
    if ((unsigned)(0 - l2) < 128u) { ISSUE8() }
  }

  for (int P = 0; P < NPH2 - 1; ++P) {
    int pn = P + 1;
    int wv = wphase(pn), l2m = l2minf(pn);
    const char* gS = g + sbase(pn);
    int rs = wv << 4;
    const char* sb0 = gS,          * sb1 = gS + rs,     * sb2 = gS + 2 * rs;
    const char* sb3 = gS + 3 * rs, * sb4 = gS + 4 * rs, * sb5 = gS + 5 * rs;
    const char* sb6 = gS + 6 * rs, * sb7 = gS + 7 * rs;
    int voff = vbase - (l2m << 4);
    bool doissue = (w == 0) ? (pn <= 190) : (pn >= 64);
    if (doissue) {
      if ((unsigned)(pn - l2) < 128u) { ISSUE8() }
      asm volatile("s_waitcnt vmcnt(8)" ::: "memory");
    } else {
      asm volatile("s_waitcnt vmcnt(0)" ::: "memory");
    }
    __builtin_amdgcn_sched_barrier(0);

    dtw_phase8(P - l2, t, w == 0, edge, L, carry, B, O, fzero, &bnd[P & 1][0]);

    if (w == 0 && t == 63) {
      #pragma unroll
      for (int k = 0; k < 9; ++k) bnd[(P + 1) & 1][k] = B[k];
      bnd[(P + 1) & 1][9] = O;
    }
    asm volatile("s_waitcnt lgkmcnt(0)" ::: "memory");
    __builtin_amdgcn_s_barrier();
    asm volatile("" ::: "memory");
  }

  // final phase P = 254 (slab loaded last iteration; hard drain)
  asm volatile("s_waitcnt vmcnt(0)" ::: "memory");
  __builtin_amdgcn_sched_barrier(0);
  dtw_phase8(254 - l2, t, w == 0, edge, L, carry, B, O, fzero,
             &bnd[254 & 1][0]);

  if (w == 1 && t == 63) out[b] = O - logf(carry[R_DP - 1]);  // R[N][M]
}

// ---------------------------------------------------------------------------
extern "C" void kernel_launch(void* const* d_in, const int* in_sizes, int n_in,
                              void* d_out, int out_size, void* d_ws, size_t ws_size,
                              hipStream_t stream) {
  const float* x = (const float*)d_in[0];
  const float* y = (const float*)d_in[1];
  float* out = (float*)d_out;

  char* ws = (char*)d_ws;
  char* Dc = ws;                                            // 32 MB compact
  size_t dp_bytes = (size_t)BATCH * BATCH_BYTES;
  unsigned short* xnb = (unsigned short*)(ws + dp_bytes);   // 4 MB
  unsigned short* ynb = xnb + (size_t)BATCH * NROW * DFEAT; // 4 MB

  norm_kernel<<<(2 * BATCH * NROW) / 4, 256, 0, stream>>>(x, y, xnb, ynb);
  dist_kernel<<<dim3(MCOL / 128, NROW / 128, BATCH), 256, 0, stream>>>(
      xnb, ynb, Dc);
  dtw_kernel<<<BATCH, 128, 0, stream>>>(Dc, out);
}